// Round 1
// baseline (1173.767 us; speedup 1.0000x reference)
//
#include <hip/hip_runtime.h>
#include <math.h>

#define BB 2
#define NN 512
#define SDIM 384
#define ZDIM 128
#define HH 12
#define CDIM 16
#define PQ 4
#define PV 8
#define BN (BB*NN)        // 1024
#define CATD 2112
#define JB 128            // j-chunk size for fused attention
#define NCH 4             // 512 / JB

#define WL  0.57735026918962576f
#define LAM 0.06804138174397717f   // wL*wC/2, wC = sqrt(2/(9*PQ))

// ---- workspace layout (float offsets) ----
#define OFF_Q    0                         // [1024][192] rows
#define OFF_QP   196608                    // [1024][144] rows
#define OFF_QQ   344064                    // [1024][12]
#define OFF_KT4  356352                    // f4: [2][48][512]  (c4-group major, n minor)
#define OFF_KPT4 552960                    // f4: [2][36][512]
#define OFF_KKT  700416                    // [2][12][512]
#define OFF_V    712704                    // [1024][192] rows (f4 view [1024][48])
#define OFF_VP   909312                    // [1024][288] rows (f4 view [1024][72])
#define OFF_CAT  7495680                   // [1024][2112]

__device__ __forceinline__ float dot4(float4 a, float4 b) {
    return a.x*b.x + a.y*b.y + a.z*b.z + a.w*b.w;
}
__device__ __forceinline__ void fma4(float4& a, float s, float4 b) {
    a.x += s*b.x; a.y += s*b.y; a.z += s*b.z; a.w += s*b.w;
}
__device__ __forceinline__ void add4(float4& a, float4 b) {
    a.x += b.x; a.y += b.y; a.z += b.z; a.w += b.w;
}
__device__ __forceinline__ void mul4(float4& a, float s) {
    a.x *= s; a.y *= s; a.z *= s; a.w *= s;
}

// ---------------- Kernel 1: projections + frame transform -------------------
__global__ __launch_bounds__(256) void k_proj(
    const float* __restrict__ s, const float* __restrict__ Rg, const float* __restrict__ tg,
    const float* __restrict__ Wq, const float* __restrict__ Wk, const float* __restrict__ Wv,
    const float* __restrict__ Wqp, const float* __restrict__ Wkp, const float* __restrict__ Wvp,
    float* __restrict__ ws)
{
    __shared__ float4 pL4[2][144];
    __shared__ float  sqL[2][96];
    __shared__ float  Rt[2][12];
    const int t = threadIdx.x;
    const int n0 = blockIdx.x * 2;
    const int b  = n0 >> 9;
    const int nloc = n0 & 511;

    if (t < 24) {
        int rr = t / 12, c = t % 12;
        Rt[rr][c] = (c < 9) ? Rg[(n0+rr)*9 + c] : tg[(n0+rr)*3 + (c-9)];
    }
    const float* s0 = s + (size_t)n0*SDIM;
    const float* s1 = s0 + SDIM;
    __syncthreads();

    float4* Q4g  = (float4*)(ws + OFF_Q);
    float4* V4g  = (float4*)(ws + OFF_V);
    float4* KT4g = (float4*)(ws + OFF_KT4);

    for (int it = 0; it < 2; ++it) {
        int g = t + it*256;
        if (g >= 288) break;
        const float4* W4; int wc4, ld4, dst;
        if (g < 48)       { W4 = (const float4*)Wq;  wc4 = g;     ld4 = 48; dst = 0; }
        else if (g < 96)  { W4 = (const float4*)Wk;  wc4 = g-48;  ld4 = 48; dst = 1; }
        else if (g < 144) { W4 = (const float4*)Wv;  wc4 = g-96;  ld4 = 48; dst = 2; }
        else if (g < 180) { W4 = (const float4*)Wqp; wc4 = g-144; ld4 = 36; dst = 3; }
        else if (g < 216) { W4 = (const float4*)Wkp; wc4 = g-180; ld4 = 36; dst = 4; }
        else              { W4 = (const float4*)Wvp; wc4 = g-216; ld4 = 72; dst = 5; }
        float4 acc0 = {0,0,0,0}, acc1 = {0,0,0,0};
        #pragma unroll 4
        for (int r = 0; r < SDIM; ++r) {
            float4 wv = W4[r*ld4 + wc4];
            float f0 = s0[r], f1 = s1[r];
            fma4(acc0, f0, wv);
            fma4(acc1, f1, wv);
        }
        if (dst == 0) {
            Q4g[(size_t)n0*48 + wc4] = acc0;
            Q4g[(size_t)(n0+1)*48 + wc4] = acc1;
        } else if (dst == 1) {
            size_t base = ((size_t)(b*48 + wc4))*512 + nloc;
            KT4g[base] = acc0; KT4g[base+1] = acc1;
        } else if (dst == 2) {
            V4g[(size_t)n0*48 + wc4] = acc0;
            V4g[(size_t)(n0+1)*48 + wc4] = acc1;
        } else if (dst == 3) {
            pL4[0][wc4] = acc0; pL4[1][wc4] = acc1;
        } else if (dst == 4) {
            pL4[0][36+wc4] = acc0; pL4[1][36+wc4] = acc1;
        } else {
            pL4[0][72+wc4] = acc0; pL4[1][72+wc4] = acc1;
        }
    }
    __syncthreads();

    for (int task = t; task < 384; task += 256) {
        int rr = task / 192, pt = task % 192;
        const float* pl = (const float*)pL4[rr];
        int off = (pt < 48) ? pt*3 : (pt < 96 ? 144 + (pt-48)*3 : 288 + (pt-96)*3);
        float p0 = pl[off], p1 = pl[off+1], p2 = pl[off+2];
        const float* R = Rt[rr];
        float g0 = R[0]*p0 + R[1]*p1 + R[2]*p2 + R[9];
        float g1 = R[3]*p0 + R[4]*p1 + R[5]*p2 + R[10];
        float g2 = R[6]*p0 + R[7]*p1 + R[8]*p2 + R[11];
        int bn = n0 + rr, n = bn & 511;
        if (pt < 48) {
            int o = pt*3;
            float* d = ws + OFF_QP + (size_t)bn*144 + o;
            d[0] = g0; d[1] = g1; d[2] = g2;
            sqL[rr][pt] = g0*g0 + g1*g1 + g2*g2;
        } else if (pt < 96) {
            int pc = (pt-48)*3;
            float gg[3] = {g0,g1,g2};
            #pragma unroll
            for (int x = 0; x < 3; ++x) {
                int pcx = pc + x;
                ws[OFF_KPT4 + (((size_t)(b*36 + (pcx>>2)))*512 + n)*4 + (pcx&3)] = gg[x];
            }
            sqL[rr][pt] = g0*g0 + g1*g1 + g2*g2;
        } else {
            int o = (pt-96)*3;
            float* d = ws + OFF_VP + (size_t)bn*288 + o;
            d[0] = g0; d[1] = g1; d[2] = g2;
        }
    }
    __syncthreads();

    if (t < 48) {
        int rr = t / 24, u = t % 24;
        int bn = n0 + rr, n = bn & 511;
        if (u < 12) {
            float sm = sqL[rr][u*4] + sqL[rr][u*4+1] + sqL[rr][u*4+2] + sqL[rr][u*4+3];
            ws[OFF_QQ + (size_t)bn*12 + u] = sm;
        } else {
            int h = u - 12;
            float sm = sqL[rr][48+h*4] + sqL[rr][48+h*4+1] + sqL[rr][48+h*4+2] + sqL[rr][48+h*4+3];
            ws[OFF_KKT + ((size_t)(b*12 + h))*512 + n] = sm;
        }
    }
}

// ---------------- Kernel 2: fused bias + flash attention per (b,i) ----------
// z is read ONCE per block, staged into LDS in 128-row chunks with coalesced
// wide loads; pair bias computed from LDS; online softmax across chunks.
__global__ __launch_bounds__(512, 4) void k_attn(
    const float* __restrict__ z, const float* __restrict__ Rg, const float* __restrict__ tg,
    const float* __restrict__ hw, const float* __restrict__ Wb, float* __restrict__ ws)
{
    // smem layout (floats):
    //   zs   [128][132]  : 0      .. 16896   (z chunk, row stride 132 for bank spread)
    //   aL   [12][132]   : 16896  .. 18480   (chunk logits -> probabilities)
    //   optg 288         : 18480  .. 18768
    //   mrun 12 | lrun 12 | fLs 12 : 18768 .. 18804
    //   RiL 9 | tiL 3    : 18804  .. 18816
    // total 18816 floats = 75264 B  -> 2 blocks/CU (150.5 KB of 160 KB LDS)
    __shared__ __align__(16) float smem[18816];
    float* zs   = smem;
    float* aL   = smem + 16896;
    float* optg = smem + 18480;
    float* mrun = smem + 18768;
    float* lrun = smem + 18780;
    float* fLs  = smem + 18792;
    float* RiL  = smem + 18804;
    float* tiL  = smem + 18813;

    const int t  = threadIdx.x;
    const int bi = blockIdx.x;
    const int b  = bi >> 9;

    if (t < 9)             RiL[t]   = Rg[bi*9 + t];
    if (t >= 9 && t < 12)  tiL[t-9] = tg[bi*3 + (t-9)];
    if (t >= 16 && t < 28) { mrun[t-16] = -1e30f; lrun[t-16] = 0.f; }

    const int jj = t >> 2;     // chunk-local j  (0..127)
    const int hq = t & 3;      // head quarter: heads {hq, hq+4, hq+8}

    // gamma = softplus(head_weights) for this thread's 3 heads
    const float g0x = hw[hq], g1x = hw[hq+4], g2x = hw[hq+8];
    const float gam0 = (g0x > 20.f) ? g0x : log1pf(__expf(g0x));
    const float gam1 = (g1x > 20.f) ? g1x : log1pf(__expf(g1x));
    const float gam2 = (g2x > 20.f) ? g2x : log1pf(__expf(g2x));

    // accumulate-phase roles (3 j-segments x 168 slot-threads)
    int seg = 0, u = 0, typ = 3, hg = 0, zc4 = 0, c4 = 0, po = 0;
    if (t < 504) {
        seg = (t >= 336) ? 2 : (t >= 168) ? 1 : 0;
        u = t - seg*168;
        if (u < 128)      { typ = 0; hg = u >> 5; zc4 = u & 31; }
        else if (u < 144) { typ = 1; hg = (u-128) >> 2; c4 = (u-128) & 3; }
        else              { typ = 2; hg = (u-144) / 6;  po = (u-144) % 6; }
    }
    const int sj0 = seg*44;
    const int sj1 = (seg == 2) ? JB : sj0 + 44;

    const float4* zg4 = (const float4*)z + (size_t)bi*NN*32;
    float4* zs4 = (float4*)zs;

    // ---- stage chunk 0: 512 thr x 8 coalesced float4 loads ----
    {
        float4 r[8];
        #pragma unroll
        for (int k2 = 0; k2 < 8; ++k2) r[k2] = zg4[t + 512*k2];
        #pragma unroll
        for (int k2 = 0; k2 < 8; ++k2) {
            int i = t + 512*k2;
            zs4[(i>>5)*33 + (i&31)] = r[k2];
        }
    }
    __syncthreads();

    const float4* Q4u  = (const float4*)(ws + OFF_Q  + (size_t)bi*192);
    const float4* QP4u = (const float4*)(ws + OFF_QP + (size_t)bi*144);
    const float*  QQu  = ws + OFF_QQ + (size_t)bi*12;
    const float4* KT4  = (const float4*)(ws + OFF_KT4)  + (size_t)b*48*512;
    const float4* KPT4 = (const float4*)(ws + OFF_KPT4) + (size_t)b*36*512;
    const float*  KKT  = ws + OFF_KKT  + (size_t)b*12*512;

    float4 acc0 = {0,0,0,0}, acc1 = {0,0,0,0}, acc2 = {0,0,0,0};

    for (int ch = 0; ch < NCH; ++ch) {
        const int j0 = ch*JB;

        // ---- logits + pair bias (from LDS z) ----
        {
            // bias partials over zc quarter [hq*32, hq*32+32) for ALL 12 heads.
            // read order rotated by +hq (float level): bank = (lane + cc) % 32 -> 2-way, free.
            float pb[12];
            #pragma unroll
            for (int h2 = 0; h2 < 12; ++h2) pb[h2] = 0.f;
            const float* zr = zs + jj*132 + hq*32;
            #pragma unroll 4
            for (int cc = 0; cc < 32; ++cc) {
                const int cq = (cc + hq) & 31;
                const float zv = zr[cq];
                const float* wr = Wb + (hq*32 + cq)*12;   // 48B-aligned, L1-hot
                const float4 w0 = *(const float4*)(wr);
                const float4 w1 = *(const float4*)(wr+4);
                const float4 w2 = *(const float4*)(wr+8);
                pb[0] += zv*w0.x; pb[1] += zv*w0.y; pb[2]  += zv*w0.z; pb[3]  += zv*w0.w;
                pb[4] += zv*w1.x; pb[5] += zv*w1.y; pb[6]  += zv*w1.z; pb[7]  += zv*w1.w;
                pb[8] += zv*w2.x; pb[9] += zv*w2.y; pb[10] += zv*w2.z; pb[11] += zv*w2.w;
            }
            // reduce the 4 hq-partials (lanes l, l^1, l^2 share j)
            #pragma unroll
            for (int h2 = 0; h2 < 12; ++h2) {
                pb[h2] += __shfl_xor(pb[h2], 1);
                pb[h2] += __shfl_xor(pb[h2], 2);
            }
            const int jg = j0 + jj;
            const float gams[3] = {gam0, gam1, gam2};
            #pragma unroll
            for (int hi = 0; hi < 3; ++hi) {
                const int h = hq + hi*4;
                float scal = 0.f, qk = 0.f;
                #pragma unroll
                for (int cg = 0; cg < 4; ++cg)
                    scal += dot4(Q4u[h*4+cg], KT4[(size_t)(h*4+cg)*512 + jg]);
                #pragma unroll
                for (int pg = 0; pg < 3; ++pg)
                    qk += dot4(QP4u[h*3+pg], KPT4[(size_t)(h*3+pg)*512 + jg]);
                const float dist2 = QQu[h] + KKT[h*512 + jg] - 2.f*qk;
                aL[h*132 + jj] = WL*(scal*0.25f + pb[h]) - LAM*gams[hi]*dist2;
            }
        }
        __syncthreads();

        // ---- online softmax over this chunk (wave per head) ----
        {
            const int w = t >> 6, lane = t & 63;
            for (int h = w; h < HH; h += 8) {
                float* row = aL + h*132;
                const float v0 = row[lane], v1 = row[lane+64];
                float mx = fmaxf(v0, v1);
                #pragma unroll
                for (int off = 32; off > 0; off >>= 1) mx = fmaxf(mx, __shfl_xor(mx, off));
                const float mo = mrun[h];
                const float mn = fmaxf(mo, mx);
                const float e0 = __expf(v0 - mn), e1 = __expf(v1 - mn);
                float ssum = e0 + e1;
                #pragma unroll
                for (int off = 32; off > 0; off >>= 1) ssum += __shfl_xor(ssum, off);
                row[lane] = e0; row[lane+64] = e1;
                if (lane == 0) {
                    const float f = __expf(mo - mn);   // chunk 0: exp(-huge) = 0
                    fLs[h]  = f;
                    mrun[h] = mn;
                    lrun[h] = lrun[h]*f + ssum;
                }
            }
        }
        __syncthreads();

        // ---- accumulate opair/o/opt_g (+ prefetch next z chunk into regs) ----
        float4 pre[8];
        if (ch < NCH-1) {
            const float4* src = zg4 + (size_t)(j0 + JB)*32;
            #pragma unroll
            for (int k2 = 0; k2 < 8; ++k2) pre[k2] = src[t + 512*k2];
        }
        if (t < 504) {
            const float f0 = fLs[hg], f1 = fLs[hg+4], f2 = fLs[hg+8];
            mul4(acc0, f0); mul4(acc1, f1); mul4(acc2, f2);
            const float* a0p = aL + hg*132;
            const float* a1p = aL + (hg+4)*132;
            const float* a2p = aL + (hg+8)*132;
            if (typ == 0) {
                for (int jt = sj0; jt < sj1; jt += 4) {
                    float4 av0 = *(const float4*)(a0p + jt);
                    float4 av1 = *(const float4*)(a1p + jt);
                    float4 av2 = *(const float4*)(a2p + jt);
                    #pragma unroll
                    for (int e = 0; e < 4; ++e) {
                        const float4 zq = zs4[(jt+e)*33 + zc4];
                        fma4(acc0, ((const float*)&av0)[e], zq);
                        fma4(acc1, ((const float*)&av1)[e], zq);
                        fma4(acc2, ((const float*)&av2)[e], zq);
                    }
                }
            } else if (typ == 1) {
                const float4* Vp = (const float4*)(ws + OFF_V) + (size_t)b*512*48;
                for (int jt = sj0; jt < sj1; jt += 4) {
                    float4 av0 = *(const float4*)(a0p + jt);
                    float4 av1 = *(const float4*)(a1p + jt);
                    float4 av2 = *(const float4*)(a2p + jt);
                    #pragma unroll
                    for (int e = 0; e < 4; ++e) {
                        const size_t jb = (size_t)(j0 + jt + e)*48;
                        fma4(acc0, ((const float*)&av0)[e], Vp[jb + (hg  )*4 + c4]);
                        fma4(acc1, ((const float*)&av1)[e], Vp[jb + (hg+4)*4 + c4]);
                        fma4(acc2, ((const float*)&av2)[e], Vp[jb + (hg+8)*4 + c4]);
                    }
                }
            } else {
                const float4* VPp = (const float4*)(ws + OFF_VP) + (size_t)b*512*72;
                for (int jt = sj0; jt < sj1; jt += 4) {
                    float4 av0 = *(const float4*)(a0p + jt);
                    float4 av1 = *(const float4*)(a1p + jt);
                    float4 av2 = *(const float4*)(a2p + jt);
                    #pragma unroll
                    for (int e = 0; e < 4; ++e) {
                        const size_t jb = (size_t)(j0 + jt + e)*72;
                        fma4(acc0, ((const float*)&av0)[e], VPp[jb + (hg  )*6 + po]);
                        fma4(acc1, ((const float*)&av1)[e], VPp[jb + (hg+4)*6 + po]);
                        fma4(acc2, ((const float*)&av2)[e], VPp[jb + (hg+8)*6 + po]);
                    }
                }
            }
        }
        __syncthreads();                  // all zs/aL readers done
        if (ch < NCH-1) {
            #pragma unroll
            for (int k2 = 0; k2 < 8; ++k2) {
                int i = t + 512*k2;
                zs4[(i>>5)*33 + (i&31)] = pre[k2];
            }
        }
        __syncthreads();                  // zs ready for next chunk (or scratch reuse)
    }

    // ---- cross-segment reduction (scratch aliases zs), normalize by l ----
    float4* sc4 = (float4*)zs;
    if (t < 504 && seg > 0) {
        const int si = ((seg-1)*168 + u)*3;
        sc4[si] = acc0; sc4[si+1] = acc1; sc4[si+2] = acc2;
    }
    __syncthreads();

    float4* optg4 = (float4*)optg;
    if (t < 168) {
        #pragma unroll
        for (int ssg = 0; ssg < 2; ++ssg) {
            const int si = (ssg*168 + t)*3;
            add4(acc0, sc4[si]); add4(acc1, sc4[si+1]); add4(acc2, sc4[si+2]);
        }
        const float iv0 = 1.f/lrun[hg];
        const float iv1 = 1.f/lrun[hg+4];
        const float iv2 = 1.f/lrun[hg+8];
        mul4(acc0, iv0); mul4(acc1, iv1); mul4(acc2, iv2);
        float4* cat4 = (float4*)(ws + OFF_CAT);
        const size_t cb = (size_t)bi * 528;          // 2112/4
        if (typ == 0) {
            cat4[cb + 144 + (hg  )*32 + zc4] = acc0;
            cat4[cb + 144 + (hg+4)*32 + zc4] = acc1;
            cat4[cb + 144 + (hg+8)*32 + zc4] = acc2;
        } else if (typ == 1) {
            cat4[cb + (hg  )*4 + c4] = acc0;
            cat4[cb + (hg+4)*4 + c4] = acc1;
            cat4[cb + (hg+8)*4 + c4] = acc2;
        } else {
            optg4[(hg  )*6 + po] = acc0;
            optg4[(hg+4)*6 + po] = acc1;
            optg4[(hg+8)*6 + po] = acc2;
        }
    }
    __syncthreads();

    if (t < 96) {
        const float* og = optg;
        const int h = t >> 3, p = t & 7;
        const int o = h*24 + p*3;
        const float d0 = og[o]   - tiL[0];
        const float d1 = og[o+1] - tiL[1];
        const float d2 = og[o+2] - tiL[2];
        const float ox = RiL[0]*d0 + RiL[3]*d1 + RiL[6]*d2;
        const float oy = RiL[1]*d0 + RiL[4]*d1 + RiL[7]*d2;
        const float oz = RiL[2]*d0 + RiL[5]*d1 + RiL[8]*d2;
        float* cat = ws + OFF_CAT + (size_t)bi*CATD;
        cat[192 + o]     = ox;
        cat[192 + o + 1] = oy;
        cat[192 + o + 2] = oz;
        cat[480 + h*8 + p] = sqrtf(ox*ox + oy*oy + oz*oz + 1e-8f);
    }
}

// ---------------- Kernel 3: out = cat @ Wout (cat via scalar loads) ---------
__global__ __launch_bounds__(384) void k_out(
    const float* __restrict__ Wout, const float* __restrict__ ws, float* __restrict__ out)
{
    const int t = threadIdx.x;                 // col 0..383
    const int row0 = blockIdx.x * 4;
    const float* c0 = ws + OFF_CAT + (size_t)(row0+0)*CATD;
    const float* c1 = c0 + CATD;
    const float* c2 = c1 + CATD;
    const float* c3 = c2 + CATD;
    float a0 = 0.f, a1 = 0.f, a2 = 0.f, a3 = 0.f;
    #pragma unroll 8
    for (int r = 0; r < CATD; ++r) {
        float w = Wout[(size_t)r*384 + t];
        a0 += c0[r]*w; a1 += c1[r]*w; a2 += c2[r]*w; a3 += c3[r]*w;
    }
    out[(size_t)(row0+0)*384 + t] = a0;
    out[(size_t)(row0+1)*384 + t] = a1;
    out[(size_t)(row0+2)*384 + t] = a2;
    out[(size_t)(row0+3)*384 + t] = a3;
}

extern "C" void kernel_launch(void* const* d_in, const int* in_sizes, int n_in,
                              void* d_out, int out_size, void* d_ws, size_t ws_size,
                              hipStream_t stream)
{
    const float* s    = (const float*)d_in[0];
    const float* z    = (const float*)d_in[1];
    const float* R    = (const float*)d_in[2];
    const float* tt   = (const float*)d_in[3];
    const float* Wq   = (const float*)d_in[4];
    const float* Wk   = (const float*)d_in[5];
    const float* Wv   = (const float*)d_in[6];
    const float* Wqp  = (const float*)d_in[7];
    const float* Wkp  = (const float*)d_in[8];
    const float* Wvp  = (const float*)d_in[9];
    const float* Wb   = (const float*)d_in[10];
    const float* hw   = (const float*)d_in[11];
    const float* Wout = (const float*)d_in[12];
    float* ws  = (float*)d_ws;
    float* out = (float*)d_out;

    hipLaunchKernelGGL(k_proj, dim3(BN/2), dim3(256), 0, stream,
                       s, R, tt, Wq, Wk, Wv, Wqp, Wkp, Wvp, ws);
    hipLaunchKernelGGL(k_attn, dim3(BN),   dim3(512), 0, stream, z, R, tt, hw, Wb, ws);
    hipLaunchKernelGGL(k_out,  dim3(BN/4), dim3(384), 0, stream, Wout, ws, out);
}